// Round 13
// baseline (512.013 us; speedup 1.0000x reference)
//
#include <hip/hip_runtime.h>
#include <hip/hip_bf16.h>
#include <cstdint>
#include <cstddef>

// Problem constants (VulnDetector): B=64, N=50000, E=300000, NF=128, G=256, H=512, R=3, L=2
constexpr int GDIM = 256;   // graph hidden
constexpr int HDIM = 512;   // fusion hidden
constexpr int NF   = 128;   // node features

typedef __attribute__((ext_vector_type(8))) short bf16x8;
typedef __attribute__((ext_vector_type(4))) float f32x4;

__device__ __forceinline__ unsigned short f2bf(float x) {
  union { float f; unsigned int u; } v; v.f = x;
  unsigned int r = v.u + 0x7FFF + ((v.u >> 16) & 1);   // RNE
  return (unsigned short)(r >> 16);
}
__device__ __forceinline__ float bf2f(unsigned int h) {
  union { unsigned int u; float f; } v; v.u = h << 16; return v.f;
}

__device__ __forceinline__ void gload16(const void* g, void* l) {
  __builtin_amdgcn_global_load_lds(
      (const __attribute__((address_space(1))) unsigned int*)g,
      (__attribute__((address_space(3))) unsigned int*)l, 16, 0, 0);
}

// ---------------- bf16 MFMA GEMM (single-buffered, m97 structure) ----------------
// out[M][ldout]bf16 = act(A[M,K]bf16 @ Wt[256,K]bf16^T + bias), NOUT=256 (ncb=2).
// 1D grid = nrb*2; bijective XCD swizzle (m204) + col-fastest decode (A panel L2-local).
// 32 KB LDS -> 5 blocks/CU; latency hidden by inter-block overlap (m114), not
// intra-block prefetch (m99/m100: explicit dbuf adds nothing and here cost 2x occupancy).
__global__ __launch_bounds__(256) void mfma_gemm(
    const unsigned short* __restrict__ A, const unsigned short* __restrict__ Wt,
    const float* __restrict__ bias, unsigned short* __restrict__ out,
    int M, int K, int ldout, int relu)
{
  __shared__ __align__(16) unsigned short lds[2 * 128 * 64];  // A 16KB | B 16KB
  char* ldsb = (char*)lds;
  const int nwg  = gridDim.x;
  const int orig = blockIdx.x;
  const int q = nwg >> 3, r = nwg & 7;
  const int xcd = orig & 7, sidx = orig >> 3;
  const int wgid = (xcd < r ? xcd * (q + 1) : r * (q + 1) + (xcd - r) * q) + sidx;
  const int row0 = (wgid >> 1) * 128;
  const int n0   = (wgid & 1) * 128;

  const int t    = threadIdx.x;
  const int lane = t & 63;
  const int w    = t >> 6;
  const int wr   = w >> 1, wc = w & 1;

  f32x4 acc[4][4] = {};

  // staging: issue i, wave w covers LDS bytes [(i*4+w)*1024, +1024), row stride 128 B
  const int srow  = lane >> 3;
  const int sslot = lane & 7;

  const int nk = K >> 6;
  for (int kt = 0; kt < nk; ++kt) {
    __syncthreads();               // readers of previous tile done before overwrite
    const int k0 = kt << 6;
#pragma unroll
    for (int i = 0; i < 4; ++i) {
      int row  = (i * 4 + w) * 8 + srow;
      int slot = sslot ^ (row & 7);            // pre-swizzled global source (m173 pattern)
      int grA  = min(row0 + row, M - 1);
      gload16(A  + (size_t)grA        * K + k0 + slot * 8, ldsb +         (i * 4 + w) * 1024);
      gload16(Wt + (size_t)(n0 + row) * K + k0 + slot * 8, ldsb + 16384 + (i * 4 + w) * 1024);
    }
    __syncthreads();               // vmcnt(0) drain + barrier: tile resident

#pragma unroll
    for (int kc = 0; kc < 2; ++kc) {
      bf16x8 af[4], bfr[4];
#pragma unroll
      for (int m = 0; m < 4; ++m) {
        int row  = wr * 64 + m * 16 + (lane & 15);
        int slot = (kc * 4 + (lane >> 4)) ^ (row & 7);   // swizzled read
        af[m] = *(const bf16x8*)(ldsb + row * 128 + slot * 16);
      }
#pragma unroll
      for (int n = 0; n < 4; ++n) {
        int row  = wc * 64 + n * 16 + (lane & 15);
        int slot = (kc * 4 + (lane >> 4)) ^ (row & 7);
        bfr[n] = *(const bf16x8*)(ldsb + 16384 + row * 128 + slot * 16);
      }
#pragma unroll
      for (int m = 0; m < 4; ++m)
#pragma unroll
        for (int n = 0; n < 4; ++n)
          acc[m][n] = __builtin_amdgcn_mfma_f32_16x16x32_bf16(af[m], bfr[n], acc[m][n], 0, 0, 0);
    }
  }

  // epilogue: C/D layout col=lane&15, row=(lane>>4)*4+reg; bf16 out, bias(+relu)
#pragma unroll
  for (int m = 0; m < 4; ++m) {
    int rbase = row0 + wr * 64 + m * 16 + (lane >> 4) * 4;
#pragma unroll
    for (int n = 0; n < 4; ++n) {
      int c = n0 + wc * 64 + n * 16 + (lane & 15);
      float badd = bias[c];
#pragma unroll
      for (int i = 0; i < 4; ++i) {
        int rr = rbase + i;
        if (rr < M) {
          float v = acc[m][n][i] + badd;
          if (relu) v = fmaxf(v, 0.f);
          out[(size_t)rr * ldout + c] = f2bf(v);
        }
      }
    }
  }
}

// ---------------- converts / weight prep ----------------
__global__ __launch_bounds__(256) void convert_bf16(
    const float* __restrict__ x, unsigned short* __restrict__ xb, int n)
{
  int i = (blockIdx.x * 256 + threadIdx.x) * 4;
  if (i >= n) return;
  float4 v = *(const float4*)(x + i);
  ushort4 o; o.x = f2bf(v.x); o.y = f2bf(v.y); o.z = f2bf(v.z); o.w = f2bf(v.w);
  *(ushort4*)(xb + i) = o;
}

// weight prep: wt_node[n][k]=node_w[k][n] (256x128); per layer K-stacked
// wtcat_l[n][k], k<256 -> self_w[l][k][n]; k>=256 -> rel_w[l][(k>>8)-1][k&255][n]
__global__ __launch_bounds__(256) void prep_all(
    const float* __restrict__ node_w, const float* __restrict__ self_w,
    const float* __restrict__ rel_w, unsigned short* __restrict__ wt_node,
    unsigned short* __restrict__ wt_l0, unsigned short* __restrict__ wt_l1)
{
  int idx = blockIdx.x * 256 + threadIdx.x;
  if (idx < 256 * 128) {
    int nn = idx >> 7, kk = idx & 127;
    wt_node[idx] = f2bf(node_w[kk * 256 + nn]);
    return;
  }
  idx -= 256 * 128;
  if (idx >= 2 * 256 * 1024) return;
  int l = idx >> 18;                       // 0..1
  int rem = idx & 262143;                  // n*1024 + k
  int nn = rem >> 10, k = rem & 1023;
  float v;
  if (k < 256) v = self_w[(size_t)l * 65536 + k * 256 + nn];
  else {
    int r = (k >> 8) - 1, kk = k & 255;
    v = rel_w[((size_t)l * 3 + r) * 65536 + kk * 256 + nn];
  }
  (l ? wt_l1 : wt_l0)[rem] = f2bf(v);
}

// ---------------- CSR build (by dst) ----------------
__global__ __launch_bounds__(256) void histo_kernel(
    const int* __restrict__ dst, int* __restrict__ deg, int E)
{
  int e = blockIdx.x * 256 + threadIdx.x;
  if (e < E) atomicAdd(&deg[dst[e]], 1);
}

__global__ __launch_bounds__(256) void scan_partial(
    const int* __restrict__ deg, int* __restrict__ incl, int* __restrict__ bsum, int N)
{
  __shared__ int s[256];
  int t = threadIdx.x;
  int n = blockIdx.x * 256 + t;
  int v = (n < N) ? deg[n] : 0;
  s[t] = v;
  __syncthreads();
#pragma unroll
  for (int o = 1; o < 256; o <<= 1) {
    int u = (t >= o) ? s[t - o] : 0;
    __syncthreads();
    s[t] += u;
    __syncthreads();
  }
  if (n < N) incl[n] = s[t];
  if (t == 255) bsum[blockIdx.x] = s[255];
}

__global__ __launch_bounds__(256) void scan_sums(int* __restrict__ bsum, int nb)
{
  __shared__ int s[256];
  int t = threadIdx.x;
  int v = (t < nb) ? bsum[t] : 0;
  s[t] = v;
  __syncthreads();
#pragma unroll
  for (int o = 1; o < 256; o <<= 1) {
    int u = (t >= o) ? s[t - o] : 0;
    __syncthreads();
    s[t] += u;
    __syncthreads();
  }
  if (t < nb) bsum[t] = s[t] - v;  // exclusive
}

__global__ __launch_bounds__(256) void scan_add(
    const int* __restrict__ incl, const int* __restrict__ deg,
    const int* __restrict__ bsum, int* __restrict__ off, int N, int E)
{
  int n = blockIdx.x * 256 + threadIdx.x;
  if (n < N) off[n] = incl[n] - deg[n] + bsum[n >> 8];
  if (n == 0) off[N] = E;
}

__global__ __launch_bounds__(256) void fill_kernel(
    const int* __restrict__ src, const int* __restrict__ dst,
    const int* __restrict__ et, const int* __restrict__ off,
    int* __restrict__ cursor, int* __restrict__ psrc, int* __restrict__ prel, int E)
{
  int e = blockIdx.x * 256 + threadIdx.x;
  if (e >= E) return;
  int d = dst[e];
  int pos = atomicAdd(&cursor[d], 1);
  int idx = off[d] + pos;
  psrc[idx] = src[e];
  prel[idx] = et[e];
}

// ---------------- pre-transform aggregation ----------------
// xcat[n][256 + r*256 + c] = sum over incoming edges (rel r) of xcat[src][c]
// (reads cols 0:256 = x; writes cols 256:1024; disjoint -> safe in-place)
// Relation is wave-uniform per edge -> uniform branch, named accumulators.
__global__ __launch_bounds__(256) void aggregate_kernel(
    const int* __restrict__ off, const int* __restrict__ psrc,
    const int* __restrict__ prel, unsigned short* __restrict__ xcat, int N)
{
  int n = blockIdx.x * 4 + (threadIdx.x >> 6);
  if (n >= N) return;
  int lane = threadIdx.x & 63;
  float4 a0 = {0.f, 0.f, 0.f, 0.f}, a1 = a0, a2 = a0;
  int i0 = off[n], i1 = off[n + 1];
  for (int i = i0; i < i1; ++i) {
    int sn = psrc[i], rr = prel[i];
    uint2 u = *(const uint2*)(xcat + (size_t)sn * 1024 + lane * 4);
    float4 v;
    v.x = bf2f(u.x & 0xFFFF); v.y = bf2f(u.x >> 16);
    v.z = bf2f(u.y & 0xFFFF); v.w = bf2f(u.y >> 16);
    if (rr == 0)      { a0.x += v.x; a0.y += v.y; a0.z += v.z; a0.w += v.w; }
    else if (rr == 1) { a1.x += v.x; a1.y += v.y; a1.z += v.z; a1.w += v.w; }
    else              { a2.x += v.x; a2.y += v.y; a2.z += v.z; a2.w += v.w; }
  }
  unsigned short* o = xcat + (size_t)n * 1024 + 256 + lane * 4;
  ushort4 s0, s1, s2;
  s0.x = f2bf(a0.x); s0.y = f2bf(a0.y); s0.z = f2bf(a0.z); s0.w = f2bf(a0.w);
  s1.x = f2bf(a1.x); s1.y = f2bf(a1.y); s1.z = f2bf(a1.z); s1.w = f2bf(a1.w);
  s2.x = f2bf(a2.x); s2.y = f2bf(a2.y); s2.z = f2bf(a2.z); s2.w = f2bf(a2.w);
  *(ushort4*)(o)       = s0;
  *(ushort4*)(o + 256) = s1;
  *(ushort4*)(o + 512) = s2;
}

// ---------------- mean-pool (input already relu'd bf16, [N][256]) ----------------
__global__ __launch_bounds__(256) void pool_kernel(
    const unsigned short* __restrict__ xb, const int* __restrict__ bv,
    float* __restrict__ hg, float* __restrict__ cnt, int N)
{
  __shared__ int sbv[128];
  int n0 = blockIdx.x * 128;
  int t = threadIdx.x;
  int nmax = min(128, N - n0);
  if (t < nmax) sbv[t] = bv[n0 + t];
  __syncthreads();
  float run = 0.f;
  int cur = sbv[0];
  for (int i = 0; i < nmax; ++i) {
    int b = sbv[i];
    if (b != cur) { atomicAdd(&hg[cur * GDIM + t], run); run = 0.f; cur = b; }
    run += bf2f(xb[(size_t)(n0 + i) * GDIM + t]);
  }
  atomicAdd(&hg[cur * GDIM + t], run);
  if (t == 0) {
    float c = 0.f; int cb = sbv[0];
    for (int i = 0; i < nmax; ++i) {
      int b = sbv[i];
      if (b != cb) { atomicAdd(&cnt[cb], c); c = 0.f; cb = b; }
      c += 1.f;
    }
    atomicAdd(&cnt[cb], c);
  }
}

// ---------------- small dense layers: split-K partials + epilogues ----------------
__global__ __launch_bounds__(256) void smallgemm_partial(
    const float* __restrict__ X, const float* __restrict__ W,
    float* __restrict__ partial, int K, int Ncols, int KC,
    const float* __restrict__ cntp)
{
  int j  = blockIdx.x * 256 + threadIdx.x;
  int b  = blockIdx.y;
  int ks = blockIdx.z;
  if (j >= Ncols) return;
  int k0 = ks * KC, k1 = min(K, k0 + KC);
  const float* xr = X + (size_t)b * K;
  float s0 = 0.f, s1 = 0.f, s2 = 0.f, s3 = 0.f;
  int k = k0;
  for (; k + 4 <= k1; k += 4) {
    s0 = fmaf(xr[k + 0], W[(size_t)(k + 0) * Ncols + j], s0);
    s1 = fmaf(xr[k + 1], W[(size_t)(k + 1) * Ncols + j], s1);
    s2 = fmaf(xr[k + 2], W[(size_t)(k + 2) * Ncols + j], s2);
    s3 = fmaf(xr[k + 3], W[(size_t)(k + 3) * Ncols + j], s3);
  }
  for (; k < k1; ++k) s0 = fmaf(xr[k], W[(size_t)k * Ncols + j], s0);
  float s = (s0 + s1) + (s2 + s3);
  if (cntp) s *= 1.f / fmaxf(cntp[b], 1.f);
  partial[((size_t)ks * gridDim.y + b) * Ncols + j] = s;
}

__global__ __launch_bounds__(256) void ep_sum(
    const float* __restrict__ partial, const float* __restrict__ bias,
    float* __restrict__ out, float* __restrict__ out2,
    int Ncols, int KS, int relu, int ld2, int off2)
{
  int j = blockIdx.x * 256 + threadIdx.x;
  int b = blockIdx.y;
  if (j >= Ncols) return;
  float s = bias ? bias[j] : 0.f;
  for (int ks = 0; ks < KS; ++ks)
    s += partial[((size_t)ks * gridDim.y + b) * Ncols + j];
  if (relu) s = fmaxf(s, 0.f);
  out[(size_t)b * Ncols + j] = s;
  if (out2) out2[(size_t)b * ld2 + off2 + j] = s;
}

__global__ __launch_bounds__(256) void ep_gate(
    const float* __restrict__ partial, const float* __restrict__ gb,
    const float* __restrict__ h, const float* __restrict__ hgp,
    float* __restrict__ f, int KS)
{
  int j = blockIdx.x * 256 + threadIdx.x;  // < 512
  int b = blockIdx.y;
  float s = gb[j];
  for (int ks = 0; ks < KS; ++ks)
    s += partial[((size_t)ks * gridDim.y + b) * HDIM + j];
  float g = 1.f / (1.f + expf(-s));
  f[(size_t)b * HDIM + j] = g * h[(size_t)b * HDIM + j] + (1.f - g) * hgp[(size_t)b * HDIM + j];
}

__global__ __launch_bounds__(256) void c2_kernel(
    const float* __restrict__ z, const float* __restrict__ w,
    const float* __restrict__ bias, float* __restrict__ out)
{
  __shared__ float r0[256], r1[256];
  int b = blockIdx.x, t = threadIdx.x;
  float zv = z[(size_t)b * 256 + t];
  r0[t] = zv * w[t * 2 + 0];
  r1[t] = zv * w[t * 2 + 1];
  __syncthreads();
  for (int o = 128; o > 0; o >>= 1) {
    if (t < o) { r0[t] += r0[t + o]; r1[t] += r1[t + o]; }
    __syncthreads();
  }
  if (t == 0) {
    out[b * 2 + 0] = r0[0] + bias[0];
    out[b * 2 + 1] = r1[0] + bias[1];
  }
}

extern "C" void kernel_launch(void* const* d_in, const int* in_sizes, int n_in,
                              void* d_out, int out_size, void* d_ws, size_t ws_size,
                              hipStream_t stream)
{
  const float* cls     = (const float*)d_in[0];
  const float* nf      = (const float*)d_in[1];
  const int*   ei      = (const int*)d_in[2];
  const int*   et      = (const int*)d_in[3];
  const int*   bv      = (const int*)d_in[4];
  const float* node_w  = (const float*)d_in[5];
  const float* node_b  = (const float*)d_in[6];
  const float* rel_w   = (const float*)d_in[7];
  const float* self_w  = (const float*)d_in[8];
  const float* self_b  = (const float*)d_in[9];
  const float* text_w  = (const float*)d_in[10];
  const float* text_b  = (const float*)d_in[11];
  const float* graph_w = (const float*)d_in[12];
  const float* graph_b = (const float*)d_in[13];
  const float* gate_w  = (const float*)d_in[14];
  const float* gate_b  = (const float*)d_in[15];
  const float* c1_w    = (const float*)d_in[16];
  const float* c1_b    = (const float*)d_in[17];
  const float* c2_w    = (const float*)d_in[18];
  const float* c2_b    = (const float*)d_in[19];

  const int Bsz = in_sizes[0] / 768;   // 64
  const int Nn  = in_sizes[1] / NF;    // 50000
  const int E   = in_sizes[3];         // 300000

  const int* src = ei;
  const int* dst = ei + E;

  // ---------------- workspace layout (floats) ----------------
  float* ws = (float*)d_ws;
  size_t off_f = 0;
  unsigned short* xcat0 = (unsigned short*)(ws + off_f); off_f += (size_t)Nn * 1024 / 2; // [N][1024]
  unsigned short* xcat1 = (unsigned short*)(ws + off_f); off_f += (size_t)Nn * 1024 / 2; // [N][1024]
  unsigned short* xbf   = (unsigned short*)(ws + off_f); off_f += (size_t)Nn * GDIM / 2; // [N][256]
  float* h   = ws + off_f; off_f += (size_t)Bsz * HDIM;
  float* hg  = ws + off_f; off_f += (size_t)Bsz * GDIM;
  float* cnt = ws + off_f; off_f += (size_t)Bsz;
  float* hgp = ws + off_f; off_f += (size_t)Bsz * HDIM;
  float* f   = ws + off_f; off_f += (size_t)Bsz * HDIM;
  float* z   = ws + off_f; off_f += (size_t)Bsz * (HDIM/2);
  float* hcat= ws + off_f; off_f += (size_t)Bsz * 2 * HDIM;
  float* pp  = ws + off_f; off_f += (size_t)8 * Bsz * HDIM;
  unsigned short* wt_node = (unsigned short*)(ws + off_f); off_f += (GDIM * NF) / 2;
  unsigned short* wt_l0   = (unsigned short*)(ws + off_f); off_f += (GDIM * 1024) / 2;
  unsigned short* wt_l1   = (unsigned short*)(ws + off_f); off_f += (GDIM * 1024) / 2;
  // persistent CSR
  int* csr_off = (int*)(ws + off_f);          // N+1
  int* psrc    = csr_off + (Nn + 1);          // E
  int* prel    = psrc + E;                    // E
  // transient CSR-build scratch overlaid on xcat1 (first written by layer-0 GEMM, later)
  int* deg    = (int*)xcat1;    // N
  int* incl   = deg + Nn;       // N
  int* cursor = incl + Nn;      // N
  int* bsum   = cursor + Nn;    // 256
  // nf bf16 overlaid on xcat1 too (dead after node GEMM; stream-ordered after fill)
  unsigned short* nfb = (unsigned short*)(cursor + Nn + 256);

  dim3 blk(256);
  const int nbN = (Nn + 255) / 256;
  const int nbE = (E + 255) / 256;
  const int nrb = (Nn + 127) / 128;    // 391 row panels
  const int KC  = 128;

  // ---------------- CSR build (once; reused by both layers) ----------------
  hipMemsetAsync(deg, 0, (size_t)(3 * Nn + 256) * sizeof(int), stream);
  histo_kernel<<<nbE, blk, 0, stream>>>(dst, deg, E);
  scan_partial<<<nbN, blk, 0, stream>>>(deg, incl, bsum, Nn);
  scan_sums<<<1, blk, 0, stream>>>(bsum, nbN);
  scan_add<<<nbN, blk, 0, stream>>>(incl, deg, bsum, csr_off, Nn, E);
  fill_kernel<<<nbE, blk, 0, stream>>>(src, dst, et, csr_off, cursor, psrc, prel, E);

  // weight prep (one launch: node + 2x K-stacked layer weights)
  prep_all<<<(256 * 128 + 2 * 256 * 1024 + 255) / 256, blk, 0, stream>>>(
      node_w, self_w, rel_w, wt_node, wt_l0, wt_l1);

  // zero pooled accumulators (hg, cnt contiguous)
  hipMemsetAsync(hg, 0, (size_t)(Bsz * GDIM + Bsz) * sizeof(float), stream);

  // text projection (split-K) -> h and hcat[:, :512]
  smallgemm_partial<<<dim3(2, Bsz, 6), blk, 0, stream>>>(cls, text_w, pp, 768, HDIM, KC, nullptr);
  ep_sum<<<dim3(2, Bsz), blk, 0, stream>>>(pp, text_b, h, hcat, HDIM, 6, 0, 2 * HDIM, 0);

  // node projection: xcat0[:, 0:256] = bf16(nf @ node_w + node_b)
  convert_bf16<<<(Nn * NF) / 4 / 256, blk, 0, stream>>>(nf, nfb, Nn * NF);
  mfma_gemm<<<dim3(nrb * 2), blk, 0, stream>>>(nfb, wt_node, node_b, xcat0, Nn, NF, 1024, 0);

  // RGCN layer 0: aggregate x per relation, then one K=1024 GEMM -> xcat1[:, 0:256] (relu)
  aggregate_kernel<<<dim3((Nn + 3) / 4), blk, 0, stream>>>(csr_off, psrc, prel, xcat0, Nn);
  mfma_gemm<<<dim3(nrb * 2), blk, 0, stream>>>(xcat0, wt_l0, self_b, xcat1, Nn, 1024, 1024, 1);

  // RGCN layer 1: aggregate, then GEMM -> xbf[:, 0:256] (relu)
  aggregate_kernel<<<dim3((Nn + 3) / 4), blk, 0, stream>>>(csr_off, psrc, prel, xcat1, Nn);
  mfma_gemm<<<dim3(nrb * 2), blk, 0, stream>>>(xcat1, wt_l1, self_b + GDIM, xbf, Nn, 1024, 256, 1);

  // mean pool (input already relu'd)
  pool_kernel<<<dim3((Nn + 127) / 128), blk, 0, stream>>>(xbf, bv, hg, cnt, Nn);

  // graph projection (mean-normalize fused via cnt) -> hgp and hcat[:, 512:]
  smallgemm_partial<<<dim3(2, Bsz, 2), blk, 0, stream>>>(hg, graph_w, pp, GDIM, HDIM, KC, cnt);
  ep_sum<<<dim3(2, Bsz), blk, 0, stream>>>(pp, graph_b, hgp, hcat, HDIM, 2, 0, 2 * HDIM, HDIM);

  // gated fusion
  smallgemm_partial<<<dim3(2, Bsz, 8), blk, 0, stream>>>(hcat, gate_w, pp, 2 * HDIM, HDIM, KC, nullptr);
  ep_gate<<<dim3(2, Bsz), blk, 0, stream>>>(pp, gate_b, h, hgp, f, 8);

  // classifier
  smallgemm_partial<<<dim3(1, Bsz, 4), blk, 0, stream>>>(f, c1_w, pp, HDIM, HDIM / 2, KC, nullptr);
  ep_sum<<<dim3(1, Bsz), blk, 0, stream>>>(pp, c1_b, z, nullptr, HDIM / 2, 4, 1, 0, 0);
  c2_kernel<<<dim3(Bsz), blk, 0, stream>>>(z, c2_w, c2_b, (float*)d_out);
}

// Round 14
// 485.510 us; speedup vs baseline: 1.0546x; 1.0546x over previous
//
#include <hip/hip_runtime.h>
#include <hip/hip_bf16.h>
#include <cstdint>
#include <cstddef>

// Problem constants (VulnDetector): B=64, N=50000, E=300000, NF=128, G=256, H=512, R=3, L=2
constexpr int GDIM = 256;   // graph hidden
constexpr int HDIM = 512;   // fusion hidden
constexpr int NF   = 128;   // node features

typedef __attribute__((ext_vector_type(8))) short bf16x8;
typedef __attribute__((ext_vector_type(4))) float f32x4;

__device__ __forceinline__ unsigned short f2bf(float x) {
  union { float f; unsigned int u; } v; v.f = x;
  unsigned int r = v.u + 0x7FFF + ((v.u >> 16) & 1);   // RNE
  return (unsigned short)(r >> 16);
}
__device__ __forceinline__ float bf2f(unsigned int h) {
  union { unsigned int u; float f; } v; v.u = h << 16; return v.f;
}

__device__ __forceinline__ void gload16(const void* g, void* l) {
  __builtin_amdgcn_global_load_lds(
      (const __attribute__((address_space(1))) unsigned int*)g,
      (__attribute__((address_space(3))) unsigned int*)l, 16, 0, 0);
}

// ---------------- bf16 MFMA GEMM (single-buffered, BM=64 for grid parallelism) ----------------
// out[M][ldout]bf16 = act(A[M,K]bf16 @ Wt[256,K]bf16^T + bias), NOUT=256 (ncb=2, BN=128).
// R13 lesson: K=1024 @ BM=128 gives only 782 blocks -> 3 waves/SIMD, latency-bound
// (Occ 17%, 1.4 TB/s). BM=64 doubles the grid to 1564 blocks (~24 waves/CU):
// LDS 24KB -> 6 blocks/CU, ~76 VGPR -> no cap. Extra B re-staging is L2-fed.
__global__ __launch_bounds__(256) void mfma_gemm(
    const unsigned short* __restrict__ A, const unsigned short* __restrict__ Wt,
    const float* __restrict__ bias, unsigned short* __restrict__ out,
    int M, int K, int ldout, int relu)
{
  __shared__ __align__(16) unsigned short lds[12288];  // A 8KB (64x64) | B 16KB (128x64)
  char* ldsb = (char*)lds;
  const int nwg  = gridDim.x;
  const int orig = blockIdx.x;
  const int q = nwg >> 3, r = nwg & 7;
  const int xcd = orig & 7, sidx = orig >> 3;
  const int wgid = (xcd < r ? xcd * (q + 1) : r * (q + 1) + (xcd - r) * q) + sidx;
  const int row0 = (wgid >> 1) * 64;
  const int n0   = (wgid & 1) * 128;

  const int t    = threadIdx.x;
  const int lane = t & 63;
  const int w    = t >> 6;
  const int wr   = w >> 1, wc = w & 1;   // wave tile: 32 rows x 64 cols

  f32x4 acc[2][4] = {};

  // staging: 24 chunks of 1024B (8 rows x 128B); chunks 0-7 A, 8-23 B
  const int srow  = lane >> 3;
  const int sslot = lane & 7;

  const int nk = K >> 6;
  for (int kt = 0; kt < nk; ++kt) {
    __syncthreads();               // readers of previous tile done before overwrite
    const int k0 = kt << 6;
#pragma unroll
    for (int i = 0; i < 6; ++i) {
      int c = i * 4 + w;                       // wave-uniform chunk id
      int rbase = (c < 8 ? c : c - 8) * 8 + srow;
      int slot  = sslot ^ (rbase & 7);         // pre-swizzled global source (m173)
      const unsigned short* src;
      if (c < 8) src = A  + (size_t)min(row0 + rbase, M - 1) * K + k0 + slot * 8;
      else       src = Wt + (size_t)(n0 + rbase)          * K + k0 + slot * 8;
      gload16(src, ldsb + c * 1024);
    }
    __syncthreads();               // vmcnt(0) drain + barrier: tile resident

#pragma unroll
    for (int kc = 0; kc < 2; ++kc) {
      bf16x8 af[2], bfr[4];
#pragma unroll
      for (int m = 0; m < 2; ++m) {
        int row  = wr * 32 + m * 16 + (lane & 15);
        int slot = (kc * 4 + (lane >> 4)) ^ (row & 7);   // swizzled read
        af[m] = *(const bf16x8*)(ldsb + row * 128 + slot * 16);
      }
#pragma unroll
      for (int n = 0; n < 4; ++n) {
        int row  = wc * 64 + n * 16 + (lane & 15);
        int slot = (kc * 4 + (lane >> 4)) ^ (row & 7);
        bfr[n] = *(const bf16x8*)(ldsb + 8192 + row * 128 + slot * 16);
      }
#pragma unroll
      for (int m = 0; m < 2; ++m)
#pragma unroll
        for (int n = 0; n < 4; ++n)
          acc[m][n] = __builtin_amdgcn_mfma_f32_16x16x32_bf16(af[m], bfr[n], acc[m][n], 0, 0, 0);
    }
  }

  // epilogue: C/D layout col=lane&15, row=(lane>>4)*4+reg; bf16 out, bias(+relu)
#pragma unroll
  for (int m = 0; m < 2; ++m) {
    int rbase = row0 + wr * 32 + m * 16 + (lane >> 4) * 4;
#pragma unroll
    for (int n = 0; n < 4; ++n) {
      int c = n0 + wc * 64 + n * 16 + (lane & 15);
      float badd = bias[c];
#pragma unroll
      for (int i = 0; i < 4; ++i) {
        int rr = rbase + i;
        if (rr < M) {
          float v = acc[m][n][i] + badd;
          if (relu) v = fmaxf(v, 0.f);
          out[(size_t)rr * ldout + c] = f2bf(v);
        }
      }
    }
  }
}

// ---------------- converts / weight prep ----------------
__global__ __launch_bounds__(256) void convert_bf16(
    const float* __restrict__ x, unsigned short* __restrict__ xb, int n)
{
  int i = (blockIdx.x * 256 + threadIdx.x) * 4;
  if (i >= n) return;
  float4 v = *(const float4*)(x + i);
  ushort4 o; o.x = f2bf(v.x); o.y = f2bf(v.y); o.z = f2bf(v.z); o.w = f2bf(v.w);
  *(ushort4*)(xb + i) = o;
}

// weight prep: wt_node[n][k]=node_w[k][n] (256x128); per layer K-stacked
// wtcat_l[n][k], k<256 -> self_w[l][k][n]; k>=256 -> rel_w[l][(k>>8)-1][k&255][n]
__global__ __launch_bounds__(256) void prep_all(
    const float* __restrict__ node_w, const float* __restrict__ self_w,
    const float* __restrict__ rel_w, unsigned short* __restrict__ wt_node,
    unsigned short* __restrict__ wt_l0, unsigned short* __restrict__ wt_l1)
{
  int idx = blockIdx.x * 256 + threadIdx.x;
  if (idx < 256 * 128) {
    int nn = idx >> 7, kk = idx & 127;
    wt_node[idx] = f2bf(node_w[kk * 256 + nn]);
    return;
  }
  idx -= 256 * 128;
  if (idx >= 2 * 256 * 1024) return;
  int l = idx >> 18;                       // 0..1
  int rem = idx & 262143;                  // n*1024 + k
  int nn = rem >> 10, k = rem & 1023;
  float v;
  if (k < 256) v = self_w[(size_t)l * 65536 + k * 256 + nn];
  else {
    int r = (k >> 8) - 1, kk = k & 255;
    v = rel_w[((size_t)l * 3 + r) * 65536 + kk * 256 + nn];
  }
  (l ? wt_l1 : wt_l0)[rem] = f2bf(v);
}

// ---------------- CSR build (by dst) ----------------
__global__ __launch_bounds__(256) void histo_kernel(
    const int* __restrict__ dst, int* __restrict__ deg, int E)
{
  int e = blockIdx.x * 256 + threadIdx.x;
  if (e < E) atomicAdd(&deg[dst[e]], 1);
}

__global__ __launch_bounds__(256) void scan_partial(
    const int* __restrict__ deg, int* __restrict__ incl, int* __restrict__ bsum, int N)
{
  __shared__ int s[256];
  int t = threadIdx.x;
  int n = blockIdx.x * 256 + t;
  int v = (n < N) ? deg[n] : 0;
  s[t] = v;
  __syncthreads();
#pragma unroll
  for (int o = 1; o < 256; o <<= 1) {
    int u = (t >= o) ? s[t - o] : 0;
    __syncthreads();
    s[t] += u;
    __syncthreads();
  }
  if (n < N) incl[n] = s[t];
  if (t == 255) bsum[blockIdx.x] = s[255];
}

__global__ __launch_bounds__(256) void scan_sums(int* __restrict__ bsum, int nb)
{
  __shared__ int s[256];
  int t = threadIdx.x;
  int v = (t < nb) ? bsum[t] : 0;
  s[t] = v;
  __syncthreads();
#pragma unroll
  for (int o = 1; o < 256; o <<= 1) {
    int u = (t >= o) ? s[t - o] : 0;
    __syncthreads();
    s[t] += u;
    __syncthreads();
  }
  if (t < nb) bsum[t] = s[t] - v;  // exclusive
}

__global__ __launch_bounds__(256) void scan_add(
    const int* __restrict__ incl, const int* __restrict__ deg,
    const int* __restrict__ bsum, int* __restrict__ off, int N, int E)
{
  int n = blockIdx.x * 256 + threadIdx.x;
  if (n < N) off[n] = incl[n] - deg[n] + bsum[n >> 8];
  if (n == 0) off[N] = E;
}

__global__ __launch_bounds__(256) void fill_kernel(
    const int* __restrict__ src, const int* __restrict__ dst,
    const int* __restrict__ et, const int* __restrict__ off,
    int* __restrict__ cursor, int* __restrict__ psrc, int* __restrict__ prel, int E)
{
  int e = blockIdx.x * 256 + threadIdx.x;
  if (e >= E) return;
  int d = dst[e];
  int pos = atomicAdd(&cursor[d], 1);
  int idx = off[d] + pos;
  psrc[idx] = src[e];
  prel[idx] = et[e];
}

// ---------------- pre-transform aggregation ----------------
// xcat[n][256 + r*256 + c] = sum over incoming edges (rel r) of xcat[src][c]
// (reads cols 0:256 = x; writes cols 256:1024; disjoint -> safe in-place)
__global__ __launch_bounds__(256) void aggregate_kernel(
    const int* __restrict__ off, const int* __restrict__ psrc,
    const int* __restrict__ prel, unsigned short* __restrict__ xcat, int N)
{
  int n = blockIdx.x * 4 + (threadIdx.x >> 6);
  if (n >= N) return;
  int lane = threadIdx.x & 63;
  float4 a0 = {0.f, 0.f, 0.f, 0.f}, a1 = a0, a2 = a0;
  int i0 = off[n], i1 = off[n + 1];
  for (int i = i0; i < i1; ++i) {
    int sn = psrc[i], rr = prel[i];
    uint2 u = *(const uint2*)(xcat + (size_t)sn * 1024 + lane * 4);
    float4 v;
    v.x = bf2f(u.x & 0xFFFF); v.y = bf2f(u.x >> 16);
    v.z = bf2f(u.y & 0xFFFF); v.w = bf2f(u.y >> 16);
    if (rr == 0)      { a0.x += v.x; a0.y += v.y; a0.z += v.z; a0.w += v.w; }
    else if (rr == 1) { a1.x += v.x; a1.y += v.y; a1.z += v.z; a1.w += v.w; }
    else              { a2.x += v.x; a2.y += v.y; a2.z += v.z; a2.w += v.w; }
  }
  unsigned short* o = xcat + (size_t)n * 1024 + 256 + lane * 4;
  ushort4 s0, s1, s2;
  s0.x = f2bf(a0.x); s0.y = f2bf(a0.y); s0.z = f2bf(a0.z); s0.w = f2bf(a0.w);
  s1.x = f2bf(a1.x); s1.y = f2bf(a1.y); s1.z = f2bf(a1.z); s1.w = f2bf(a1.w);
  s2.x = f2bf(a2.x); s2.y = f2bf(a2.y); s2.z = f2bf(a2.z); s2.w = f2bf(a2.w);
  *(ushort4*)(o)       = s0;
  *(ushort4*)(o + 256) = s1;
  *(ushort4*)(o + 512) = s2;
}

// ---------------- mean-pool (input already relu'd bf16, [N][256]) ----------------
__global__ __launch_bounds__(256) void pool_kernel(
    const unsigned short* __restrict__ xb, const int* __restrict__ bv,
    float* __restrict__ hg, float* __restrict__ cnt, int N)
{
  __shared__ int sbv[128];
  int n0 = blockIdx.x * 128;
  int t = threadIdx.x;
  int nmax = min(128, N - n0);
  if (t < nmax) sbv[t] = bv[n0 + t];
  __syncthreads();
  float run = 0.f;
  int cur = sbv[0];
  for (int i = 0; i < nmax; ++i) {
    int b = sbv[i];
    if (b != cur) { atomicAdd(&hg[cur * GDIM + t], run); run = 0.f; cur = b; }
    run += bf2f(xb[(size_t)(n0 + i) * GDIM + t]);
  }
  atomicAdd(&hg[cur * GDIM + t], run);
  if (t == 0) {
    float c = 0.f; int cb = sbv[0];
    for (int i = 0; i < nmax; ++i) {
      int b = sbv[i];
      if (b != cb) { atomicAdd(&cnt[cb], c); c = 0.f; cb = b; }
      c += 1.f;
    }
    atomicAdd(&cnt[cb], c);
  }
}

// ---------------- small dense layers: split-K partials + epilogues ----------------
__global__ __launch_bounds__(256) void smallgemm_partial(
    const float* __restrict__ X, const float* __restrict__ W,
    float* __restrict__ partial, int K, int Ncols, int KC,
    const float* __restrict__ cntp)
{
  int j  = blockIdx.x * 256 + threadIdx.x;
  int b  = blockIdx.y;
  int ks = blockIdx.z;
  if (j >= Ncols) return;
  int k0 = ks * KC, k1 = min(K, k0 + KC);
  const float* xr = X + (size_t)b * K;
  float s0 = 0.f, s1 = 0.f, s2 = 0.f, s3 = 0.f;
  int k = k0;
  for (; k + 4 <= k1; k += 4) {
    s0 = fmaf(xr[k + 0], W[(size_t)(k + 0) * Ncols + j], s0);
    s1 = fmaf(xr[k + 1], W[(size_t)(k + 1) * Ncols + j], s1);
    s2 = fmaf(xr[k + 2], W[(size_t)(k + 2) * Ncols + j], s2);
    s3 = fmaf(xr[k + 3], W[(size_t)(k + 3) * Ncols + j], s3);
  }
  for (; k < k1; ++k) s0 = fmaf(xr[k], W[(size_t)k * Ncols + j], s0);
  float s = (s0 + s1) + (s2 + s3);
  if (cntp) s *= 1.f / fmaxf(cntp[b], 1.f);
  partial[((size_t)ks * gridDim.y + b) * Ncols + j] = s;
}

__global__ __launch_bounds__(256) void ep_sum(
    const float* __restrict__ partial, const float* __restrict__ bias,
    float* __restrict__ out, float* __restrict__ out2,
    int Ncols, int KS, int relu, int ld2, int off2)
{
  int j = blockIdx.x * 256 + threadIdx.x;
  int b = blockIdx.y;
  if (j >= Ncols) return;
  float s = bias ? bias[j] : 0.f;
  for (int ks = 0; ks < KS; ++ks)
    s += partial[((size_t)ks * gridDim.y + b) * Ncols + j];
  if (relu) s = fmaxf(s, 0.f);
  out[(size_t)b * Ncols + j] = s;
  if (out2) out2[(size_t)b * ld2 + off2 + j] = s;
}

__global__ __launch_bounds__(256) void ep_gate(
    const float* __restrict__ partial, const float* __restrict__ gb,
    const float* __restrict__ h, const float* __restrict__ hgp,
    float* __restrict__ f, int KS)
{
  int j = blockIdx.x * 256 + threadIdx.x;  // < 512
  int b = blockIdx.y;
  float s = gb[j];
  for (int ks = 0; ks < KS; ++ks)
    s += partial[((size_t)ks * gridDim.y + b) * HDIM + j];
  float g = 1.f / (1.f + expf(-s));
  f[(size_t)b * HDIM + j] = g * h[(size_t)b * HDIM + j] + (1.f - g) * hgp[(size_t)b * HDIM + j];
}

__global__ __launch_bounds__(256) void c2_kernel(
    const float* __restrict__ z, const float* __restrict__ w,
    const float* __restrict__ bias, float* __restrict__ out)
{
  __shared__ float r0[256], r1[256];
  int b = blockIdx.x, t = threadIdx.x;
  float zv = z[(size_t)b * 256 + t];
  r0[t] = zv * w[t * 2 + 0];
  r1[t] = zv * w[t * 2 + 1];
  __syncthreads();
  for (int o = 128; o > 0; o >>= 1) {
    if (t < o) { r0[t] += r0[t + o]; r1[t] += r1[t + o]; }
    __syncthreads();
  }
  if (t == 0) {
    out[b * 2 + 0] = r0[0] + bias[0];
    out[b * 2 + 1] = r1[0] + bias[1];
  }
}

extern "C" void kernel_launch(void* const* d_in, const int* in_sizes, int n_in,
                              void* d_out, int out_size, void* d_ws, size_t ws_size,
                              hipStream_t stream)
{
  const float* cls     = (const float*)d_in[0];
  const float* nf      = (const float*)d_in[1];
  const int*   ei      = (const int*)d_in[2];
  const int*   et      = (const int*)d_in[3];
  const int*   bv      = (const int*)d_in[4];
  const float* node_w  = (const float*)d_in[5];
  const float* node_b  = (const float*)d_in[6];
  const float* rel_w   = (const float*)d_in[7];
  const float* self_w  = (const float*)d_in[8];
  const float* self_b  = (const float*)d_in[9];
  const float* text_w  = (const float*)d_in[10];
  const float* text_b  = (const float*)d_in[11];
  const float* graph_w = (const float*)d_in[12];
  const float* graph_b = (const float*)d_in[13];
  const float* gate_w  = (const float*)d_in[14];
  const float* gate_b  = (const float*)d_in[15];
  const float* c1_w    = (const float*)d_in[16];
  const float* c1_b    = (const float*)d_in[17];
  const float* c2_w    = (const float*)d_in[18];
  const float* c2_b    = (const float*)d_in[19];

  const int Bsz = in_sizes[0] / 768;   // 64
  const int Nn  = in_sizes[1] / NF;    // 50000
  const int E   = in_sizes[3];         // 300000

  const int* src = ei;
  const int* dst = ei + E;

  // ---------------- workspace layout (floats) ----------------
  float* ws = (float*)d_ws;
  size_t off_f = 0;
  unsigned short* xcat0 = (unsigned short*)(ws + off_f); off_f += (size_t)Nn * 1024 / 2; // [N][1024]
  unsigned short* xcat1 = (unsigned short*)(ws + off_f); off_f += (size_t)Nn * 1024 / 2; // [N][1024]
  unsigned short* xbf   = (unsigned short*)(ws + off_f); off_f += (size_t)Nn * GDIM / 2; // [N][256]
  float* h   = ws + off_f; off_f += (size_t)Bsz * HDIM;
  float* hg  = ws + off_f; off_f += (size_t)Bsz * GDIM;
  float* cnt = ws + off_f; off_f += (size_t)Bsz;
  float* hgp = ws + off_f; off_f += (size_t)Bsz * HDIM;
  float* f   = ws + off_f; off_f += (size_t)Bsz * HDIM;
  float* z   = ws + off_f; off_f += (size_t)Bsz * (HDIM/2);
  float* hcat= ws + off_f; off_f += (size_t)Bsz * 2 * HDIM;
  float* pp  = ws + off_f; off_f += (size_t)8 * Bsz * HDIM;
  unsigned short* wt_node = (unsigned short*)(ws + off_f); off_f += (GDIM * NF) / 2;
  unsigned short* wt_l0   = (unsigned short*)(ws + off_f); off_f += (GDIM * 1024) / 2;
  unsigned short* wt_l1   = (unsigned short*)(ws + off_f); off_f += (GDIM * 1024) / 2;
  // persistent CSR
  int* csr_off = (int*)(ws + off_f);          // N+1
  int* psrc    = csr_off + (Nn + 1);          // E
  int* prel    = psrc + E;                    // E
  // transient CSR-build scratch overlaid on xcat1 (first written by layer-0 GEMM, later)
  int* deg    = (int*)xcat1;    // N
  int* incl   = deg + Nn;       // N
  int* cursor = incl + Nn;      // N
  int* bsum   = cursor + Nn;    // 256
  // nf bf16 overlaid on xcat1 too (dead after node GEMM; stream-ordered after fill)
  unsigned short* nfb = (unsigned short*)(cursor + Nn + 256);

  dim3 blk(256);
  const int nbN = (Nn + 255) / 256;
  const int nbE = (E + 255) / 256;
  const int nrb = (Nn + 63) / 64;      // 782 row panels (BM=64)
  const int KC  = 128;

  // ---------------- CSR build (once; reused by both layers) ----------------
  hipMemsetAsync(deg, 0, (size_t)(3 * Nn + 256) * sizeof(int), stream);
  histo_kernel<<<nbE, blk, 0, stream>>>(dst, deg, E);
  scan_partial<<<nbN, blk, 0, stream>>>(deg, incl, bsum, Nn);
  scan_sums<<<1, blk, 0, stream>>>(bsum, nbN);
  scan_add<<<nbN, blk, 0, stream>>>(incl, deg, bsum, csr_off, Nn, E);
  fill_kernel<<<nbE, blk, 0, stream>>>(src, dst, et, csr_off, cursor, psrc, prel, E);

  // weight prep (one launch: node + 2x K-stacked layer weights)
  prep_all<<<(256 * 128 + 2 * 256 * 1024 + 255) / 256, blk, 0, stream>>>(
      node_w, self_w, rel_w, wt_node, wt_l0, wt_l1);

  // zero pooled accumulators (hg, cnt contiguous)
  hipMemsetAsync(hg, 0, (size_t)(Bsz * GDIM + Bsz) * sizeof(float), stream);

  // text projection (split-K) -> h and hcat[:, :512]
  smallgemm_partial<<<dim3(2, Bsz, 6), blk, 0, stream>>>(cls, text_w, pp, 768, HDIM, KC, nullptr);
  ep_sum<<<dim3(2, Bsz), blk, 0, stream>>>(pp, text_b, h, hcat, HDIM, 6, 0, 2 * HDIM, 0);

  // node projection: xcat0[:, 0:256] = bf16(nf @ node_w + node_b)
  convert_bf16<<<(Nn * NF) / 4 / 256, blk, 0, stream>>>(nf, nfb, Nn * NF);
  mfma_gemm<<<dim3(nrb * 2), blk, 0, stream>>>(nfb, wt_node, node_b, xcat0, Nn, NF, 1024, 0);

  // RGCN layer 0: aggregate x per relation, then one K=1024 GEMM -> xcat1[:, 0:256] (relu)
  aggregate_kernel<<<dim3((Nn + 3) / 4), blk, 0, stream>>>(csr_off, psrc, prel, xcat0, Nn);
  mfma_gemm<<<dim3(nrb * 2), blk, 0, stream>>>(xcat0, wt_l0, self_b, xcat1, Nn, 1024, 1024, 1);

  // RGCN layer 1: aggregate, then GEMM -> xbf[:, 0:256] (relu)
  aggregate_kernel<<<dim3((Nn + 3) / 4), blk, 0, stream>>>(csr_off, psrc, prel, xcat1, Nn);
  mfma_gemm<<<dim3(nrb * 2), blk, 0, stream>>>(xcat1, wt_l1, self_b + GDIM, xbf, Nn, 1024, 256, 1);

  // mean pool (input already relu'd)
  pool_kernel<<<dim3((Nn + 127) / 128), blk, 0, stream>>>(xbf, bv, hg, cnt, Nn);

  // graph projection (mean-normalize fused via cnt) -> hgp and hcat[:, 512:]
  smallgemm_partial<<<dim3(2, Bsz, 2), blk, 0, stream>>>(hg, graph_w, pp, GDIM, HDIM, KC, cnt);
  ep_sum<<<dim3(2, Bsz), blk, 0, stream>>>(pp, graph_b, hgp, hcat, HDIM, 2, 0, 2 * HDIM, HDIM);

  // gated fusion
  smallgemm_partial<<<dim3(2, Bsz, 8), blk, 0, stream>>>(hcat, gate_w, pp, 2 * HDIM, HDIM, KC, nullptr);
  ep_gate<<<dim3(2, Bsz), blk, 0, stream>>>(pp, gate_b, h, hgp, f, 8);

  // classifier
  smallgemm_partial<<<dim3(1, Bsz, 4), blk, 0, stream>>>(f, c1_w, pp, HDIM, HDIM / 2, KC, nullptr);
  ep_sum<<<dim3(1, Bsz), blk, 0, stream>>>(pp, c1_b, z, nullptr, HDIM / 2, 4, 1, 0, 0);
  c2_kernel<<<dim3(Bsz), blk, 0, stream>>>(z, c2_w, c2_b, (float*)d_out);
}

// Round 15
// 431.147 us; speedup vs baseline: 1.1876x; 1.1261x over previous
//
#include <hip/hip_runtime.h>
#include <hip/hip_bf16.h>
#include <cstdint>
#include <cstddef>

// Problem constants (VulnDetector): B=64, N=50000, E=300000, NF=128, G=256, H=512, R=3, L=2
constexpr int GDIM = 256;   // graph hidden
constexpr int HDIM = 512;   // fusion hidden
constexpr int NF   = 128;   // node features

typedef __attribute__((ext_vector_type(8))) short bf16x8;
typedef __attribute__((ext_vector_type(4))) float f32x4;

__device__ __forceinline__ unsigned short f2bf(float x) {
  union { float f; unsigned int u; } v; v.f = x;
  unsigned int r = v.u + 0x7FFF + ((v.u >> 16) & 1);   // RNE
  return (unsigned short)(r >> 16);
}
__device__ __forceinline__ float bf2f(unsigned int h) {
  union { unsigned int u; float f; } v; v.u = h << 16; return v.f;
}

__device__ __forceinline__ void gload16(const void* g, void* l) {
  __builtin_amdgcn_global_load_lds(
      (const __attribute__((address_space(1))) unsigned int*)g,
      (__attribute__((address_space(3))) unsigned int*)l, 16, 0, 0);
}

// ---------------- bf16 MFMA GEMM (single-buffered, BM=64 for grid parallelism) ----------------
// out[M][ldout]bf16 = act(A[M,K]bf16 @ Wt[256,K]bf16^T + bias), NOUT=256 (ncb=2, BN=128).
__global__ __launch_bounds__(256) void mfma_gemm(
    const unsigned short* __restrict__ A, const unsigned short* __restrict__ Wt,
    const float* __restrict__ bias, unsigned short* __restrict__ out,
    int M, int K, int ldout, int relu)
{
  __shared__ __align__(16) unsigned short lds[12288];  // A 8KB (64x64) | B 16KB (128x64)
  char* ldsb = (char*)lds;
  const int nwg  = gridDim.x;
  const int orig = blockIdx.x;
  const int q = nwg >> 3, r = nwg & 7;
  const int xcd = orig & 7, sidx = orig >> 3;
  const int wgid = (xcd < r ? xcd * (q + 1) : r * (q + 1) + (xcd - r) * q) + sidx;
  const int row0 = (wgid >> 1) * 64;
  const int n0   = (wgid & 1) * 128;

  const int t    = threadIdx.x;
  const int lane = t & 63;
  const int w    = t >> 6;
  const int wr   = w >> 1, wc = w & 1;   // wave tile: 32 rows x 64 cols

  f32x4 acc[2][4] = {};

  // staging: 24 chunks of 1024B (8 rows x 128B); chunks 0-7 A, 8-23 B
  const int srow  = lane >> 3;
  const int sslot = lane & 7;

  const int nk = K >> 6;
  for (int kt = 0; kt < nk; ++kt) {
    __syncthreads();               // readers of previous tile done before overwrite
    const int k0 = kt << 6;
#pragma unroll
    for (int i = 0; i < 6; ++i) {
      int c = i * 4 + w;                       // wave-uniform chunk id
      int rbase = (c < 8 ? c : c - 8) * 8 + srow;
      int slot  = sslot ^ (rbase & 7);         // pre-swizzled global source (m173)
      const unsigned short* src;
      if (c < 8) src = A  + (size_t)min(row0 + rbase, M - 1) * K + k0 + slot * 8;
      else       src = Wt + (size_t)(n0 + rbase)          * K + k0 + slot * 8;
      gload16(src, ldsb + c * 1024);
    }
    __syncthreads();               // vmcnt(0) drain + barrier: tile resident

#pragma unroll
    for (int kc = 0; kc < 2; ++kc) {
      bf16x8 af[2], bfr[4];
#pragma unroll
      for (int m = 0; m < 2; ++m) {
        int row  = wr * 32 + m * 16 + (lane & 15);
        int slot = (kc * 4 + (lane >> 4)) ^ (row & 7);   // swizzled read
        af[m] = *(const bf16x8*)(ldsb + row * 128 + slot * 16);
      }
#pragma unroll
      for (int n = 0; n < 4; ++n) {
        int row  = wc * 64 + n * 16 + (lane & 15);
        int slot = (kc * 4 + (lane >> 4)) ^ (row & 7);
        bfr[n] = *(const bf16x8*)(ldsb + 8192 + row * 128 + slot * 16);
      }
#pragma unroll
      for (int m = 0; m < 2; ++m)
#pragma unroll
        for (int n = 0; n < 4; ++n)
          acc[m][n] = __builtin_amdgcn_mfma_f32_16x16x32_bf16(af[m], bfr[n], acc[m][n], 0, 0, 0);
    }
  }

  // epilogue: C/D layout col=lane&15, row=(lane>>4)*4+reg; bf16 out, bias(+relu)
#pragma unroll
  for (int m = 0; m < 2; ++m) {
    int rbase = row0 + wr * 32 + m * 16 + (lane >> 4) * 4;
#pragma unroll
    for (int n = 0; n < 4; ++n) {
      int c = n0 + wc * 64 + n * 16 + (lane & 15);
      float badd = bias[c];
#pragma unroll
      for (int i = 0; i < 4; ++i) {
        int rr = rbase + i;
        if (rr < M) {
          float v = acc[m][n][i] + badd;
          if (relu) v = fmaxf(v, 0.f);
          out[(size_t)rr * ldout + c] = f2bf(v);
        }
      }
    }
  }
}

// ---------------- converts / weight prep ----------------
__global__ __launch_bounds__(256) void convert_bf16(
    const float* __restrict__ x, unsigned short* __restrict__ xb, int n)
{
  int i = (blockIdx.x * 256 + threadIdx.x) * 4;
  if (i >= n) return;
  float4 v = *(const float4*)(x + i);
  ushort4 o; o.x = f2bf(v.x); o.y = f2bf(v.y); o.z = f2bf(v.z); o.w = f2bf(v.w);
  *(ushort4*)(xb + i) = o;
}

// weight prep: wt_node[n][k]=node_w[k][n] (256x128); per layer K-stacked
__global__ __launch_bounds__(256) void prep_all(
    const float* __restrict__ node_w, const float* __restrict__ self_w,
    const float* __restrict__ rel_w, unsigned short* __restrict__ wt_node,
    unsigned short* __restrict__ wt_l0, unsigned short* __restrict__ wt_l1)
{
  int idx = blockIdx.x * 256 + threadIdx.x;
  if (idx < 256 * 128) {
    int nn = idx >> 7, kk = idx & 127;
    wt_node[idx] = f2bf(node_w[kk * 256 + nn]);
    return;
  }
  idx -= 256 * 128;
  if (idx >= 2 * 256 * 1024) return;
  int l = idx >> 18;                       // 0..1
  int rem = idx & 262143;                  // n*1024 + k
  int nn = rem >> 10, k = rem & 1023;
  float v;
  if (k < 256) v = self_w[(size_t)l * 65536 + k * 256 + nn];
  else {
    int r = (k >> 8) - 1, kk = k & 255;
    v = rel_w[((size_t)l * 3 + r) * 65536 + kk * 256 + nn];
  }
  (l ? wt_l1 : wt_l0)[rem] = f2bf(v);
}

// ---------------- CSR build (by dst) ----------------
__global__ __launch_bounds__(256) void histo_kernel(
    const int* __restrict__ dst, int* __restrict__ deg, int E)
{
  int e = blockIdx.x * 256 + threadIdx.x;
  if (e < E) atomicAdd(&deg[dst[e]], 1);
}

__global__ __launch_bounds__(256) void scan_partial(
    const int* __restrict__ deg, int* __restrict__ incl, int* __restrict__ bsum, int N)
{
  __shared__ int s[256];
  int t = threadIdx.x;
  int n = blockIdx.x * 256 + t;
  int v = (n < N) ? deg[n] : 0;
  s[t] = v;
  __syncthreads();
#pragma unroll
  for (int o = 1; o < 256; o <<= 1) {
    int u = (t >= o) ? s[t - o] : 0;
    __syncthreads();
    s[t] += u;
    __syncthreads();
  }
  if (n < N) incl[n] = s[t];
  if (t == 255) bsum[blockIdx.x] = s[255];
}

__global__ __launch_bounds__(256) void scan_sums(int* __restrict__ bsum, int nb)
{
  __shared__ int s[256];
  int t = threadIdx.x;
  int v = (t < nb) ? bsum[t] : 0;
  s[t] = v;
  __syncthreads();
#pragma unroll
  for (int o = 1; o < 256; o <<= 1) {
    int u = (t >= o) ? s[t - o] : 0;
    __syncthreads();
    s[t] += u;
    __syncthreads();
  }
  if (t < nb) bsum[t] = s[t] - v;  // exclusive
}

__global__ __launch_bounds__(256) void scan_add(
    const int* __restrict__ incl, const int* __restrict__ deg,
    const int* __restrict__ bsum, int* __restrict__ off, int N, int E)
{
  int n = blockIdx.x * 256 + threadIdx.x;
  if (n < N) off[n] = incl[n] - deg[n] + bsum[n >> 8];
  if (n == 0) off[N] = E;
}

// packed edge word: src | (rel << 20)   (N < 2^20, rel < 3)
__global__ __launch_bounds__(256) void fill_kernel(
    const int* __restrict__ src, const int* __restrict__ dst,
    const int* __restrict__ et, const int* __restrict__ off,
    int* __restrict__ cursor, int* __restrict__ pedge, int E)
{
  int e = blockIdx.x * 256 + threadIdx.x;
  if (e >= E) return;
  int d = dst[e];
  int pos = atomicAdd(&cursor[d], 1);
  pedge[off[d] + pos] = src[e] | (et[e] << 20);
}

// ---------------- pre-transform aggregation (4-deep MLP) ----------------
// xcat[n][256 + r*256 + c] = sum over incoming edges (rel r) of xcat[src][c]
__global__ __launch_bounds__(256) void aggregate_kernel(
    const int* __restrict__ off, const int* __restrict__ pedge,
    unsigned short* __restrict__ xcat, int N)
{
  int n = blockIdx.x * 4 + (threadIdx.x >> 6);
  if (n >= N) return;
  int lane = threadIdx.x & 63;
  float4 a0 = {0.f, 0.f, 0.f, 0.f}, a1 = a0, a2 = a0;
  int i0 = off[n], i1 = off[n + 1];

#define GATHER(p) (*(const uint2*)(xcat + (size_t)((p) & 0xFFFFF) * 1024 + lane * 4))
#define ACCUM(u, r)                                                        \
  {                                                                        \
    float4 v;                                                              \
    v.x = bf2f((u).x & 0xFFFF); v.y = bf2f((u).x >> 16);                   \
    v.z = bf2f((u).y & 0xFFFF); v.w = bf2f((u).y >> 16);                   \
    if ((r) == 0)      { a0.x += v.x; a0.y += v.y; a0.z += v.z; a0.w += v.w; } \
    else if ((r) == 1) { a1.x += v.x; a1.y += v.y; a1.z += v.z; a1.w += v.w; } \
    else               { a2.x += v.x; a2.y += v.y; a2.z += v.z; a2.w += v.w; } \
  }

  int i = i0;
  for (; i + 4 <= i1; i += 4) {
    int p0 = pedge[i + 0], p1 = pedge[i + 1], p2 = pedge[i + 2], p3 = pedge[i + 3];
    uint2 u0 = GATHER(p0);   // 4 independent gathers in flight
    uint2 u1 = GATHER(p1);
    uint2 u2 = GATHER(p2);
    uint2 u3 = GATHER(p3);
    ACCUM(u0, p0 >> 20); ACCUM(u1, p1 >> 20);
    ACCUM(u2, p2 >> 20); ACCUM(u3, p3 >> 20);
  }
  for (; i < i1; ++i) {
    int p = pedge[i];
    uint2 u = GATHER(p);
    ACCUM(u, p >> 20);
  }
#undef GATHER
#undef ACCUM

  unsigned short* o = xcat + (size_t)n * 1024 + 256 + lane * 4;
  ushort4 s0, s1, s2;
  s0.x = f2bf(a0.x); s0.y = f2bf(a0.y); s0.z = f2bf(a0.z); s0.w = f2bf(a0.w);
  s1.x = f2bf(a1.x); s1.y = f2bf(a1.y); s1.z = f2bf(a1.z); s1.w = f2bf(a1.w);
  s2.x = f2bf(a2.x); s2.y = f2bf(a2.y); s2.z = f2bf(a2.z); s2.w = f2bf(a2.w);
  *(ushort4*)(o)       = s0;
  *(ushort4*)(o + 256) = s1;
  *(ushort4*)(o + 512) = s2;
}

// ---------------- mean-pool (32 nodes/block for parallelism) ----------------
__global__ __launch_bounds__(256) void pool_kernel(
    const unsigned short* __restrict__ xb, const int* __restrict__ bv,
    float* __restrict__ hg, float* __restrict__ cnt, int N)
{
  __shared__ int sbv[32];
  int n0 = blockIdx.x * 32;
  int t = threadIdx.x;
  int nmax = min(32, N - n0);
  if (t < nmax) sbv[t] = bv[n0 + t];
  __syncthreads();
  float run = 0.f;
  int cur = sbv[0];
  for (int i = 0; i < nmax; ++i) {
    int b = sbv[i];
    if (b != cur) { atomicAdd(&hg[cur * GDIM + t], run); run = 0.f; cur = b; }
    run += bf2f(xb[(size_t)(n0 + i) * GDIM + t]);
  }
  atomicAdd(&hg[cur * GDIM + t], run);
  if (t == 0) {
    float c = 0.f; int cb = sbv[0];
    for (int i = 0; i < nmax; ++i) {
      int b = sbv[i];
      if (b != cb) { atomicAdd(&cnt[cb], c); c = 0.f; cb = b; }
      c += 1.f;
    }
    atomicAdd(&cnt[cb], c);
  }
}

// ---------------- small dense layers: split-K partials + epilogues ----------------
__global__ __launch_bounds__(256) void smallgemm_partial(
    const float* __restrict__ X, const float* __restrict__ W,
    float* __restrict__ partial, int K, int Ncols, int KC,
    const float* __restrict__ cntp)
{
  int j  = blockIdx.x * 256 + threadIdx.x;
  int b  = blockIdx.y;
  int ks = blockIdx.z;
  if (j >= Ncols) return;
  int k0 = ks * KC, k1 = min(K, k0 + KC);
  const float* xr = X + (size_t)b * K;
  float s0 = 0.f, s1 = 0.f, s2 = 0.f, s3 = 0.f;
  int k = k0;
  for (; k + 4 <= k1; k += 4) {
    s0 = fmaf(xr[k + 0], W[(size_t)(k + 0) * Ncols + j], s0);
    s1 = fmaf(xr[k + 1], W[(size_t)(k + 1) * Ncols + j], s1);
    s2 = fmaf(xr[k + 2], W[(size_t)(k + 2) * Ncols + j], s2);
    s3 = fmaf(xr[k + 3], W[(size_t)(k + 3) * Ncols + j], s3);
  }
  for (; k < k1; ++k) s0 = fmaf(xr[k], W[(size_t)k * Ncols + j], s0);
  float s = (s0 + s1) + (s2 + s3);
  if (cntp) s *= 1.f / fmaxf(cntp[b], 1.f);
  partial[((size_t)ks * gridDim.y + b) * Ncols + j] = s;
}

__global__ __launch_bounds__(256) void ep_sum(
    const float* __restrict__ partial, const float* __restrict__ bias,
    float* __restrict__ out, float* __restrict__ out2,
    int Ncols, int KS, int relu, int ld2, int off2)
{
  int j = blockIdx.x * 256 + threadIdx.x;
  int b = blockIdx.y;
  if (j >= Ncols) return;
  float s = bias ? bias[j] : 0.f;
  for (int ks = 0; ks < KS; ++ks)
    s += partial[((size_t)ks * gridDim.y + b) * Ncols + j];
  if (relu) s = fmaxf(s, 0.f);
  out[(size_t)b * Ncols + j] = s;
  if (out2) out2[(size_t)b * ld2 + off2 + j] = s;
}

__global__ __launch_bounds__(256) void ep_gate(
    const float* __restrict__ partial, const float* __restrict__ gb,
    const float* __restrict__ h, const float* __restrict__ hgp,
    float* __restrict__ f, int KS)
{
  int j = blockIdx.x * 256 + threadIdx.x;  // < 512
  int b = blockIdx.y;
  float s = gb[j];
  for (int ks = 0; ks < KS; ++ks)
    s += partial[((size_t)ks * gridDim.y + b) * HDIM + j];
  float g = 1.f / (1.f + expf(-s));
  f[(size_t)b * HDIM + j] = g * h[(size_t)b * HDIM + j] + (1.f - g) * hgp[(size_t)b * HDIM + j];
}

__global__ __launch_bounds__(256) void c2_kernel(
    const float* __restrict__ z, const float* __restrict__ w,
    const float* __restrict__ bias, float* __restrict__ out)
{
  __shared__ float r0[256], r1[256];
  int b = blockIdx.x, t = threadIdx.x;
  float zv = z[(size_t)b * 256 + t];
  r0[t] = zv * w[t * 2 + 0];
  r1[t] = zv * w[t * 2 + 1];
  __syncthreads();
  for (int o = 128; o > 0; o >>= 1) {
    if (t < o) { r0[t] += r0[t + o]; r1[t] += r1[t + o]; }
    __syncthreads();
  }
  if (t == 0) {
    out[b * 2 + 0] = r0[0] + bias[0];
    out[b * 2 + 1] = r1[0] + bias[1];
  }
}

extern "C" void kernel_launch(void* const* d_in, const int* in_sizes, int n_in,
                              void* d_out, int out_size, void* d_ws, size_t ws_size,
                              hipStream_t stream)
{
  const float* cls     = (const float*)d_in[0];
  const float* nf      = (const float*)d_in[1];
  const int*   ei      = (const int*)d_in[2];
  const int*   et      = (const int*)d_in[3];
  const int*   bv      = (const int*)d_in[4];
  const float* node_w  = (const float*)d_in[5];
  const float* node_b  = (const float*)d_in[6];
  const float* rel_w   = (const float*)d_in[7];
  const float* self_w  = (const float*)d_in[8];
  const float* self_b  = (const float*)d_in[9];
  const float* text_w  = (const float*)d_in[10];
  const float* text_b  = (const float*)d_in[11];
  const float* graph_w = (const float*)d_in[12];
  const float* graph_b = (const float*)d_in[13];
  const float* gate_w  = (const float*)d_in[14];
  const float* gate_b  = (const float*)d_in[15];
  const float* c1_w    = (const float*)d_in[16];
  const float* c1_b    = (const float*)d_in[17];
  const float* c2_w    = (const float*)d_in[18];
  const float* c2_b    = (const float*)d_in[19];

  const int Bsz = in_sizes[0] / 768;   // 64
  const int Nn  = in_sizes[1] / NF;    // 50000
  const int E   = in_sizes[3];         // 300000

  const int* src = ei;
  const int* dst = ei + E;

  // ---------------- workspace layout (floats) ----------------
  float* ws = (float*)d_ws;
  size_t off_f = 0;
  unsigned short* xcat0 = (unsigned short*)(ws + off_f); off_f += (size_t)Nn * 1024 / 2; // [N][1024]
  unsigned short* xcat1 = (unsigned short*)(ws + off_f); off_f += (size_t)Nn * 1024 / 2; // [N][1024]
  unsigned short* xbf   = (unsigned short*)(ws + off_f); off_f += (size_t)Nn * GDIM / 2; // [N][256]
  float* h   = ws + off_f; off_f += (size_t)Bsz * HDIM;
  float* hg  = ws + off_f; off_f += (size_t)Bsz * GDIM;
  float* cnt = ws + off_f; off_f += (size_t)Bsz;
  float* hgp = ws + off_f; off_f += (size_t)Bsz * HDIM;
  float* f   = ws + off_f; off_f += (size_t)Bsz * HDIM;
  float* z   = ws + off_f; off_f += (size_t)Bsz * (HDIM/2);
  float* hcat= ws + off_f; off_f += (size_t)Bsz * 2 * HDIM;
  float* pp  = ws + off_f; off_f += (size_t)8 * Bsz * HDIM;
  unsigned short* wt_node = (unsigned short*)(ws + off_f); off_f += (GDIM * NF) / 2;
  unsigned short* wt_l0   = (unsigned short*)(ws + off_f); off_f += (GDIM * 1024) / 2;
  unsigned short* wt_l1   = (unsigned short*)(ws + off_f); off_f += (GDIM * 1024) / 2;
  // persistent CSR
  int* csr_off = (int*)(ws + off_f);          // N+1
  int* pedge   = csr_off + (Nn + 1);          // E (packed src|rel<<20)
  // transient CSR-build scratch overlaid on xcat1 (first written by layer-0 GEMM, later)
  int* deg    = (int*)xcat1;    // N
  int* incl   = deg + Nn;       // N
  int* cursor = incl + Nn;      // N
  int* bsum   = cursor + Nn;    // 256
  // nf bf16 overlaid on xcat1 too (dead after node GEMM; stream-ordered after fill)
  unsigned short* nfb = (unsigned short*)(cursor + Nn + 256);

  dim3 blk(256);
  const int nbN = (Nn + 255) / 256;
  const int nbE = (E + 255) / 256;
  const int nrb = (Nn + 63) / 64;      // 782 row panels (BM=64)
  const int KC  = 128;

  // ---------------- CSR build (once; reused by both layers) ----------------
  hipMemsetAsync(deg, 0, (size_t)(3 * Nn + 256) * sizeof(int), stream);
  histo_kernel<<<nbE, blk, 0, stream>>>(dst, deg, E);
  scan_partial<<<nbN, blk, 0, stream>>>(deg, incl, bsum, Nn);
  scan_sums<<<1, blk, 0, stream>>>(bsum, nbN);
  scan_add<<<nbN, blk, 0, stream>>>(incl, deg, bsum, csr_off, Nn, E);
  fill_kernel<<<nbE, blk, 0, stream>>>(src, dst, et, csr_off, cursor, pedge, E);

  // weight prep (one launch: node + 2x K-stacked layer weights)
  prep_all<<<(256 * 128 + 2 * 256 * 1024 + 255) / 256, blk, 0, stream>>>(
      node_w, self_w, rel_w, wt_node, wt_l0, wt_l1);

  // zero pooled accumulators (hg, cnt contiguous)
  hipMemsetAsync(hg, 0, (size_t)(Bsz * GDIM + Bsz) * sizeof(float), stream);

  // text projection (split-K) -> h and hcat[:, :512]
  smallgemm_partial<<<dim3(2, Bsz, 6), blk, 0, stream>>>(cls, text_w, pp, 768, HDIM, KC, nullptr);
  ep_sum<<<dim3(2, Bsz), blk, 0, stream>>>(pp, text_b, h, hcat, HDIM, 6, 0, 2 * HDIM, 0);

  // node projection: xcat0[:, 0:256] = bf16(nf @ node_w + node_b)
  convert_bf16<<<(Nn * NF) / 4 / 256, blk, 0, stream>>>(nf, nfb, Nn * NF);
  mfma_gemm<<<dim3(nrb * 2), blk, 0, stream>>>(nfb, wt_node, node_b, xcat0, Nn, NF, 1024, 0);

  // RGCN layer 0: aggregate x per relation, then one K=1024 GEMM -> xcat1[:, 0:256] (relu)
  aggregate_kernel<<<dim3((Nn + 3) / 4), blk, 0, stream>>>(csr_off, pedge, xcat0, Nn);
  mfma_gemm<<<dim3(nrb * 2), blk, 0, stream>>>(xcat0, wt_l0, self_b, xcat1, Nn, 1024, 1024, 1);

  // RGCN layer 1: aggregate, then GEMM -> xbf[:, 0:256] (relu)
  aggregate_kernel<<<dim3((Nn + 3) / 4), blk, 0, stream>>>(csr_off, pedge, xcat1, Nn);
  mfma_gemm<<<dim3(nrb * 2), blk, 0, stream>>>(xcat1, wt_l1, self_b + GDIM, xbf, Nn, 1024, 256, 1);

  // mean pool (input already relu'd)
  pool_kernel<<<dim3((Nn + 31) / 32), blk, 0, stream>>>(xbf, bv, hg, cnt, Nn);

  // graph projection (mean-normalize fused via cnt) -> hgp and hcat[:, 512:]
  smallgemm_partial<<<dim3(2, Bsz, 2), blk, 0, stream>>>(hg, graph_w, pp, GDIM, HDIM, KC, cnt);
  ep_sum<<<dim3(2, Bsz), blk, 0, stream>>>(pp, graph_b, hgp, hcat, HDIM, 2, 0, 2 * HDIM, HDIM);

  // gated fusion
  smallgemm_partial<<<dim3(2, Bsz, 8), blk, 0, stream>>>(hcat, gate_w, pp, 2 * HDIM, HDIM, KC, nullptr);
  ep_gate<<<dim3(2, Bsz), blk, 0, stream>>>(pp, gate_b, h, hgp, f, 8);

  // classifier
  smallgemm_partial<<<dim3(1, Bsz, 4), blk, 0, stream>>>(f, c1_w, pp, HDIM, HDIM / 2, KC, nullptr);
  ep_sum<<<dim3(1, Bsz), blk, 0, stream>>>(pp, c1_b, z, nullptr, HDIM / 2, 4, 1, 0, 0);
  c2_kernel<<<dim3(Bsz), blk, 0, stream>>>(z, c2_w, c2_b, (float*)d_out);
}